// Round 16
// baseline (2590.091 us; speedup 1.0000x reference)
//
#include <hip/hip_runtime.h>
#include <stdint.h>
#include <math.h>

// Replicate jax.random threefry2x32 exactly (jax_threefry_partitionable=True).
#define PARTITIONABLE 1

namespace {

constexpr int kB = 4096;
constexpr int kN = 256;
constexpr int kSweeps = 200;
constexpr int kSamp = 16;                // samples per block (two octets)
constexpr int kBlocks = kB / kSamp;      // 256 blocks of 512 threads -> 1/CU
// r13 (measured best) + 4-deep J prefetch window + setprio around matvec.
// block = 8 waves: waves 0-3 consumers (wave cw: sample-octet cw&1,
// row-half cw>>1, 2 rows/thread), waves 4-7 producers (next sweep threefry).
// Wave w -> SIMD w%4 gives every SIMD exactly 1 consumer + 1 producer.

struct K2 { uint32_t a, b; };

__host__ __device__ constexpr uint32_t crotl(uint32_t x, int d) {
  return (x << d) | (x >> (32 - d));
}

// Threefry-2x32, 20 rounds, exactly as jax/_src/prng.py
__host__ __device__ constexpr K2 ctf(uint32_t k0, uint32_t k1, uint32_t c0, uint32_t c1) {
  uint32_t ks0 = k0, ks1 = k1, ks2 = k0 ^ k1 ^ 0x1BD11BDAu;
  uint32_t x0 = c0 + ks0, x1 = c1 + ks1;
  const int r0[4] = {13, 15, 26, 6};
  const int r1[4] = {17, 29, 16, 24};
  for (int i = 0; i < 4; ++i) { x0 += x1; x1 = crotl(x1, r0[i]); x1 ^= x0; }
  x0 += ks1; x1 += ks2 + 1u;
  for (int i = 0; i < 4; ++i) { x0 += x1; x1 = crotl(x1, r1[i]); x1 ^= x0; }
  x0 += ks2; x1 += ks0 + 2u;
  for (int i = 0; i < 4; ++i) { x0 += x1; x1 = crotl(x1, r0[i]); x1 ^= x0; }
  x0 += ks0; x1 += ks1 + 3u;
  for (int i = 0; i < 4; ++i) { x0 += x1; x1 = crotl(x1, r1[i]); x1 ^= x0; }
  x0 += ks1; x1 += ks2 + 4u;
  for (int i = 0; i < 4; ++i) { x0 += x1; x1 = crotl(x1, r0[i]); x1 ^= x0; }
  x0 += ks2; x1 += ks0 + 5u;
  return K2{x0, x1};
}

struct KeyTable {
  uint32_t s0k[2];               // key for initial spins (k0)
  uint32_t sk[kSweeps][4];       // per sweep: k1a,k1b (accept), k2a,k2b (mask)
};

constexpr KeyTable make_keys() {
  KeyTable t{};
  K2 root{0u, 42u};              // jax.random.key(42) -> (hi=0, lo=42)
#if PARTITIONABLE
  K2 k0 = ctf(root.a, root.b, 0u, 0u);
  K2 kl = ctf(root.a, root.b, 0u, 1u);
#else
  K2 p0 = ctf(root.a, root.b, 0u, 2u);
  K2 p1 = ctf(root.a, root.b, 1u, 3u);
  K2 k0{p0.a, p1.a};
  K2 kl{p0.b, p1.b};
#endif
  t.s0k[0] = k0.a; t.s0k[1] = k0.b;
  K2 k = kl;
  for (int s = 0; s < kSweeps; ++s) {
#if PARTITIONABLE
    K2 kn = ctf(k.a, k.b, 0u, 0u);
    K2 k1 = ctf(k.a, k.b, 0u, 1u);
    K2 k2 = ctf(k.a, k.b, 0u, 2u);
#else
    K2 q0 = ctf(k.a, k.b, 0u, 3u);
    K2 q1 = ctf(k.a, k.b, 1u, 4u);
    K2 q2 = ctf(k.a, k.b, 2u, 5u);
    K2 kn{q0.a, q1.a};
    K2 k1{q2.a, q0.b};
    K2 k2{q1.b, q2.b};
#endif
    t.sk[s][0] = k1.a; t.sk[s][1] = k1.b;
    t.sk[s][2] = k2.a; t.sk[s][3] = k2.b;
    k = kn;
  }
  return t;
}

__constant__ KeyTable g_keys = make_keys();

__device__ __forceinline__ uint32_t rng_bits32(uint32_t ka, uint32_t kb, uint32_t m) {
#if PARTITIONABLE
  K2 r = ctf(ka, kb, 0u, m);
  return r.a ^ r.b;
#else
  constexpr uint32_t H = (uint32_t)(kB * kN / 2);
  uint32_t p = (m < H) ? m : (m - H);
  K2 r = ctf(ka, kb, p, p + H);
  return (m < H) ? r.a : r.b;
#endif
}

__device__ __forceinline__ float bits_to_uniform(uint32_t bits) {
  // jax: bitcast(bits >> 9 | 0x3f800000) - 1.0
  return __uint_as_float((bits >> 9) | 0x3f800000u) - 1.0f;
}

// prep: betas + coalesced-permuted J (r13 layout, harness-verified).
// float4 idx = rh*8192 + c*256 + slot*64 + l2, comp = f&3
//   where rh=i>>7, l2=(i&127)>>1, r=i&1, c=j>>3, f=j&7, slot=r*2+(f>>2);
//   holds Jsym[rh*128 + 2*l2 + r][8c + 4*(slot&1) + comp].
// A load of (rh,c,slot) across 64 lanes (l2=lane) reads 64 contiguous
// float4 = 1 KB = 16 cachelines.
__global__ void prep_kernel(const float* __restrict__ gamma,
                            float* __restrict__ jp,
                            float* __restrict__ betas) {
  int e = blockIdx.x * blockDim.x + threadIdx.x;   // 0..65535
  int i = e / kN, j = e % kN;
  float v = 0.0f;
  if (i < j) v = gamma[i * kN + j];
  else if (i > j) v = gamma[j * kN + i];
  int rh = i >> 7, l2 = (i & 127) >> 1, r = i & 1, c = j >> 3, f = j & 7;
  int slot = r * 2 + (f >> 2);
  jp[(((size_t)rh * 8192 + c * 256 + slot * 64 + l2) << 2) + (f & 3)] = v;
  if (e < kSweeps) {
    double lo = log(0.1), hi = log(5.0);
    betas[e] = (float)exp(lo + (hi - lo) * (double)e / (double)(kSweeps - 1));
  }
}

// One VALU op per element: f32 fma with the f16 spin operand converted in-op.
// Conversion of +-1.0h to f32 is exact, then fp32 fma -> bit-identical to
// fmaf(+-1.0f, J, acc). op_sel picks lo/hi half of the packed u32.
#define FMIX_LO(a, w, j)                                                      \
  asm("v_fma_mix_f32 %0, %1, %2, %0 op_sel:[0,0,0] op_sel_hi:[1,0,0]"         \
      : "+v"(a) : "v"(w), "v"(j))
#define FMIX_HI(a, w, j)                                                      \
  asm("v_fma_mix_f32 %0, %1, %2, %0 op_sel:[1,0,0] op_sel_hi:[1,0,0]"         \
      : "+v"(a) : "v"(w), "v"(j))

__global__ __launch_bounds__(512) void anneal_kernel(
    const float* __restrict__ thetas, const float* __restrict__ jp,
    const float* __restrict__ betas, float* __restrict__ out) {
  // fp16 spins (+1.0h=0x3C00, -1.0h=0xBC00), [buf][g][row], dbuf: 16 KiB
  __shared__ __align__(16) unsigned short sh_h[2][kSamp][kN];
  // packed randoms w = ((b1>>9)<<1)|(b2>>31), one u32/site, dbuf: 32 KiB
  __shared__ __align__(16) uint32_t sh_rand[2][kSamp * kN];
  __shared__ float sh_red[kSamp][4];

  const int tid = threadIdx.x;
  const int lane = tid & 63;
  const int wvid = tid >> 6;                     // wave 0..7 -> SIMD wvid%4
  const bool consumer = (wvid < 4);
  const int b0 = blockIdx.x * kSamp;             // first sample of block

  int cur = 0;

  if (consumer) {
    const int cw = wvid;                         // consumer wave 0..3
    const int oct = cw & 1;                      // sample octet 0/1
    const int rh = cw >> 1;                      // row half 0/1
    const int gbase = oct * 8;                   // first sample of octet
    const int row0 = rh * 128 + 2 * lane;        // rows row0, row0+1

    // th_[2g+r] = theta of (sample gbase+g, row r); sreg[g] = fp16 spin pair
    float th_[16];
    uint32_t sreg[8];
#pragma unroll
    for (int g = 0; g < 8; ++g) {
      float2 t2 = *(const float2*)&thetas[(b0 + gbase + g) * kN + row0];
      th_[2 * g] = t2.x; th_[2 * g + 1] = t2.y;
    }
    // s0 = where(bernoulli(k0, 0.5), 1, -1) ; bernoulli = uniform < 0.5
#pragma unroll
    for (int g = 0; g < 8; ++g) {
      uint32_t m0 = (uint32_t)((b0 + gbase + g) * kN + row0);
      float u0 = bits_to_uniform(rng_bits32(g_keys.s0k[0], g_keys.s0k[1], m0));
      float u1 = bits_to_uniform(rng_bits32(g_keys.s0k[0], g_keys.s0k[1], m0 + 1));
      uint32_t pk = ((u0 < 0.5f) ? 0x3C00u : 0xBC00u) |
                    (((u1 < 0.5f) ? 0x3C00u : 0xBC00u) << 16);
      sreg[g] = pk;
      *(uint32_t*)&sh_h[0][gbase + g][row0] = pk;
    }
    __syncthreads();

    // coalesced J slice: slot s of chunk c at jpt[c*256 + s*64] (lane-contig)
    const float4* __restrict__ jpt =
        (const float4*)jp + (size_t)rh * 8192 + (size_t)lane;

#define LDSPIN(g, c) (*(const uint4*)&sh_h[cur][gbase + (g)][(c) * 8])
#define LDJ(Jw, c)                                                            \
    Jw[0] = jpt[(c) * 256 + 0];   Jw[1] = jpt[(c) * 256 + 64];                \
    Jw[2] = jpt[(c) * 256 + 128]; Jw[3] = jpt[(c) * 256 + 192];
    // consume chunk (8 j) for 8 samples x 2 rows: 128 fma_mix, j ascending
#define CONSUME2(W, Q)                                                        \
  _Pragma("unroll")                                                           \
  for (int g = 0; g < 8; ++g) {                                               \
    FMIX_LO(acc[2*g], W[g].x, Q[0].x); FMIX_HI(acc[2*g], W[g].x, Q[0].y);     \
    FMIX_LO(acc[2*g], W[g].y, Q[0].z); FMIX_HI(acc[2*g], W[g].y, Q[0].w);     \
    FMIX_LO(acc[2*g], W[g].z, Q[1].x); FMIX_HI(acc[2*g], W[g].z, Q[1].y);     \
    FMIX_LO(acc[2*g], W[g].w, Q[1].z); FMIX_HI(acc[2*g], W[g].w, Q[1].w);     \
    FMIX_LO(acc[2*g+1], W[g].x, Q[2].x); FMIX_HI(acc[2*g+1], W[g].x, Q[2].y); \
    FMIX_LO(acc[2*g+1], W[g].y, Q[2].z); FMIX_HI(acc[2*g+1], W[g].y, Q[2].w); \
    FMIX_LO(acc[2*g+1], W[g].z, Q[3].x); FMIX_HI(acc[2*g+1], W[g].z, Q[3].y); \
    FMIX_LO(acc[2*g+1], W[g].w, Q[3].z); FMIX_HI(acc[2*g+1], W[g].w, Q[3].w); \
  }
    // matvec: spins A/B 1-chunk-ahead (LDS, short latency); J 4-deep
    // rotating window J0..J3 (~768 cyc cover for L2-latency stream head).
    // Rolled 7-iter x 4-chunk body (fixed register shape, r13 style).
#define MATVEC(acc)                                                           \
  {                                                                           \
    uint4 A[8], Bw[8];                                                        \
    float4 J0[4], J1[4], J2[4], J3[4];                                        \
    _Pragma("unroll")                                                         \
    for (int g = 0; g < 8; ++g) A[g] = LDSPIN(g, 0);                          \
    LDJ(J0, 0) LDJ(J1, 1) LDJ(J2, 2) LDJ(J3, 3)                               \
    _Pragma("unroll 1")                                                       \
    for (int k = 0; k < 7; ++k) {                                             \
      const int c = 4 * k;                                                    \
      _Pragma("unroll")                                                       \
      for (int g = 0; g < 8; ++g) Bw[g] = LDSPIN(g, c + 1);                   \
      CONSUME2(A, J0)  LDJ(J0, c + 4)                                         \
      _Pragma("unroll")                                                       \
      for (int g = 0; g < 8; ++g) A[g] = LDSPIN(g, c + 2);                    \
      CONSUME2(Bw, J1) LDJ(J1, c + 5)                                         \
      _Pragma("unroll")                                                       \
      for (int g = 0; g < 8; ++g) Bw[g] = LDSPIN(g, c + 3);                   \
      CONSUME2(A, J2)  LDJ(J2, c + 6)                                         \
      _Pragma("unroll")                                                       \
      for (int g = 0; g < 8; ++g) A[g] = LDSPIN(g, c + 4);                    \
      CONSUME2(Bw, J3) LDJ(J3, c + 7)                                         \
    }                                                                         \
    /* tail: chunks 28..31; A=spins(28), J0..J3 = J(28..31) */                \
    _Pragma("unroll")                                                         \
    for (int g = 0; g < 8; ++g) Bw[g] = LDSPIN(g, 29);                        \
    CONSUME2(A, J0)                                                           \
    _Pragma("unroll")                                                         \
    for (int g = 0; g < 8; ++g) A[g] = LDSPIN(g, 30);                         \
    CONSUME2(Bw, J1)                                                          \
    _Pragma("unroll")                                                         \
    for (int g = 0; g < 8; ++g) Bw[g] = LDSPIN(g, 31);                        \
    CONSUME2(A, J2)                                                           \
    CONSUME2(Bw, J3)                                                          \
  }

#pragma unroll 1
    for (int t = 0; t < kSweeps; ++t) {
      const float beta = betas[t];
      // randoms for this sweep (produced last sweep / prologue): 2 sites/g
      uint2 wp[8];
      {
        const uint32_t* __restrict__ rb =
            &sh_rand[t & 1][gbase * kN + rh * 128 + 2 * lane];
#pragma unroll
        for (int g = 0; g < 8; ++g)
          wp[g] = *(const uint2*)&rb[g * kN];
      }

      float acc[16];
#pragma unroll
      for (int x = 0; x < 16; ++x) acc[x] = 0.0f;
      __builtin_amdgcn_s_setprio(1);     // T5: favor consumer over producer
      MATVEC(acc)
      __builtin_amdgcn_s_setprio(0);

#pragma unroll
      for (int g = 0; g < 8; ++g) {
        uint32_t pk = sreg[g];
        float s0f = __uint_as_float(0x3F800000u | ((pk << 16) & 0x80000000u));
        float s1f = __uint_as_float(0x3F800000u | (pk & 0x80000000u));
        float l0 = th_[2 * g] + acc[2 * g];
        float l1 = th_[2 * g + 1] + acc[2 * g + 1];
        float d0 = -2.0f * s0f * l0;       // exact: (-2*s) power of two
        float d1 = -2.0f * s1f * l1;
        float p0 = expf(-beta * d0);
        float p1 = expf(-beta * d1);
        float u0 = __uint_as_float((wp[g].x >> 1) | 0x3f800000u) - 1.0f;
        float u1 = __uint_as_float((wp[g].y >> 1) | 0x3f800000u) - 1.0f;
        uint32_t msk = 0u;
        if ((u0 < p0) && ((wp[g].x & 1u) == 0u)) msk |= 0x8000u;
        if ((u1 < p1) && ((wp[g].y & 1u) == 0u)) msk |= 0x80000000u;
        pk ^= msk;                          // flip = fp16 sign flip
        sreg[g] = pk;
        *(uint32_t*)&sh_h[cur ^ 1][gbase + g][row0] = pk;
      }
      __syncthreads();
      cur ^= 1;
    }

    // E_b = sum_i s_i*theta_i + 0.5 * sum_i s_i * (Jsym s)_i
    {
      float acc[16];
#pragma unroll
      for (int x = 0; x < 16; ++x) acc[x] = 0.0f;
      __builtin_amdgcn_s_setprio(1);
      MATVEC(acc)
      __builtin_amdgcn_s_setprio(0);

#pragma unroll
      for (int g = 0; g < 8; ++g) {
        uint32_t pk = sreg[g];
        float s0f = __uint_as_float(0x3F800000u | ((pk << 16) & 0x80000000u));
        float s1f = __uint_as_float(0x3F800000u | (pk & 0x80000000u));
        // identical expression to previous rounds: v = s*th + 0.5f*(s*acc)
        float x0 = s0f * th_[2 * g] + 0.5f * (s0f * acc[2 * g]);
        float x1 = s1f * th_[2 * g + 1] + 0.5f * (s1f * acc[2 * g + 1]);
        // slot-split tree == r13 == original 64-lane shfl tree
#pragma unroll
        for (int off = 16; off > 0; off >>= 1) {
          x0 += __shfl_down(x0, off);
          x1 += __shfl_down(x1, off);
        }
        float v = x0 + x1;
        if (lane == 0)  sh_red[gbase + g][2 * rh + 0] = v;  // rows [rh*128,+64)
        if (lane == 32) sh_red[gbase + g][2 * rh + 1] = v;  // rows [rh*128+64,+64)
      }
    }
  } else {
    // ---------------- producer waves (4..7), r13-verified ----------------
    // store instruction k covers sites pw*1024 + k*256 + lane*4 + 0..3:
    // lane-contiguous 16B -> conflict-free ds_write_b128.
    const int pw = wvid - 4;                       // 0..3
    {
      const uint32_t k1a = g_keys.sk[0][0], k1b = g_keys.sk[0][1];
      const uint32_t k2a = g_keys.sk[0][2], k2b = g_keys.sk[0][3];
#pragma unroll
      for (int k = 0; k < 4; ++k) {
        const uint32_t site = (uint32_t)(pw * 1024 + k * 256 + lane * 4);
        const uint32_t mb = (uint32_t)(b0 * kN) + site;
        uint32_t wv[4];
#pragma unroll
        for (int e = 0; e < 4; ++e) {
          uint32_t b1 = rng_bits32(k1a, k1b, mb + e);
          uint32_t b2 = rng_bits32(k2a, k2b, mb + e);
          wv[e] = ((b1 >> 9) << 1) | (b2 >> 31);
        }
        uint4 v; v.x = wv[0]; v.y = wv[1]; v.z = wv[2]; v.w = wv[3];
        *(uint4*)&sh_rand[0][site] = v;
      }
    }
    __syncthreads();

#pragma unroll 1
    for (int t = 0; t < kSweeps; ++t) {
      if (t + 1 < kSweeps) {
        const uint32_t k1a = g_keys.sk[t + 1][0], k1b = g_keys.sk[t + 1][1];
        const uint32_t k2a = g_keys.sk[t + 1][2], k2b = g_keys.sk[t + 1][3];
#pragma unroll
        for (int k = 0; k < 4; ++k) {
          const uint32_t site = (uint32_t)(pw * 1024 + k * 256 + lane * 4);
          const uint32_t mb = (uint32_t)(b0 * kN) + site;
          uint32_t wv[4];
#pragma unroll
          for (int e = 0; e < 4; ++e) {
            uint32_t b1 = rng_bits32(k1a, k1b, mb + e);
            uint32_t b2 = rng_bits32(k2a, k2b, mb + e);
            wv[e] = ((b1 >> 9) << 1) | (b2 >> 31);
          }
          uint4 v; v.x = wv[0]; v.y = wv[1]; v.z = wv[2]; v.w = wv[3];
          *(uint4*)&sh_rand[(t + 1) & 1][site] = v;
        }
      }
      __syncthreads();
    }
  }

  __syncthreads();
  if (tid < kSamp) {
    out[b0 + tid] =
        sh_red[tid][0] + sh_red[tid][1] + sh_red[tid][2] + sh_red[tid][3];
  }
}

}  // namespace

extern "C" void kernel_launch(void* const* d_in, const int* in_sizes, int n_in,
                              void* d_out, int out_size, void* d_ws, size_t ws_size,
                              hipStream_t stream) {
  const float* thetas = (const float*)d_in[0];   // [4096, 256]
  const float* gamma  = (const float*)d_in[1];   // [256, 256]
  char* ws = (char*)d_ws;
  float* jp    = (float*)ws;                               // 256 KiB
  float* betas = (float*)(ws + (size_t)kN * kN * 4);       // 800 B

  hipLaunchKernelGGL(prep_kernel, dim3(kN), dim3(kN), 0, stream,
                     gamma, jp, betas);
  hipLaunchKernelGGL(anneal_kernel, dim3(kBlocks), dim3(512), 0, stream,
                     thetas, jp, betas, (float*)d_out);
}

// Round 17
// 2213.486 us; speedup vs baseline: 1.1701x; 1.1701x over previous
//
#include <hip/hip_runtime.h>
#include <stdint.h>
#include <math.h>

// Replicate jax.random threefry2x32 exactly (jax_threefry_partitionable=True).
#define PARTITIONABLE 1

namespace {

constexpr int kB = 4096;
constexpr int kN = 256;
constexpr int kSweeps = 200;
constexpr int kSamp = 16;                // samples per block (two octets)
constexpr int kBlocks = kB / kSamp;      // 256 blocks of 512 threads -> 1/CU
// r13 verbatim (measured session best, 2211 us):
//  (1) J layout coalesced: each load instruction reads 64 contiguous float4.
//  (2) producer sh_rand stores lane-contiguous (16B/lane) -> 0 bank conflicts.
// block = 8 waves: waves 0-3 consumers (wave cw: sample-octet cw&1,
// row-half cw>>1, 2 rows/thread), waves 4-7 producers (next sweep threefry).
// Wave w -> SIMD w%4 gives every SIMD exactly 1 consumer + 1 producer.
// Rejected by measurement: 4-deep J window / setprio (r16, -8%), readlane
// wave-private (r12/r14), (4,4) row-split (r11/r15 neutral-to-worse).

struct K2 { uint32_t a, b; };

__host__ __device__ constexpr uint32_t crotl(uint32_t x, int d) {
  return (x << d) | (x >> (32 - d));
}

// Threefry-2x32, 20 rounds, exactly as jax/_src/prng.py
__host__ __device__ constexpr K2 ctf(uint32_t k0, uint32_t k1, uint32_t c0, uint32_t c1) {
  uint32_t ks0 = k0, ks1 = k1, ks2 = k0 ^ k1 ^ 0x1BD11BDAu;
  uint32_t x0 = c0 + ks0, x1 = c1 + ks1;
  const int r0[4] = {13, 15, 26, 6};
  const int r1[4] = {17, 29, 16, 24};
  for (int i = 0; i < 4; ++i) { x0 += x1; x1 = crotl(x1, r0[i]); x1 ^= x0; }
  x0 += ks1; x1 += ks2 + 1u;
  for (int i = 0; i < 4; ++i) { x0 += x1; x1 = crotl(x1, r1[i]); x1 ^= x0; }
  x0 += ks2; x1 += ks0 + 2u;
  for (int i = 0; i < 4; ++i) { x0 += x1; x1 = crotl(x1, r0[i]); x1 ^= x0; }
  x0 += ks0; x1 += ks1 + 3u;
  for (int i = 0; i < 4; ++i) { x0 += x1; x1 = crotl(x1, r1[i]); x1 ^= x0; }
  x0 += ks1; x1 += ks2 + 4u;
  for (int i = 0; i < 4; ++i) { x0 += x1; x1 = crotl(x1, r0[i]); x1 ^= x0; }
  x0 += ks2; x1 += ks0 + 5u;
  return K2{x0, x1};
}

struct KeyTable {
  uint32_t s0k[2];               // key for initial spins (k0)
  uint32_t sk[kSweeps][4];       // per sweep: k1a,k1b (accept), k2a,k2b (mask)
};

constexpr KeyTable make_keys() {
  KeyTable t{};
  K2 root{0u, 42u};              // jax.random.key(42) -> (hi=0, lo=42)
#if PARTITIONABLE
  K2 k0 = ctf(root.a, root.b, 0u, 0u);
  K2 kl = ctf(root.a, root.b, 0u, 1u);
#else
  K2 p0 = ctf(root.a, root.b, 0u, 2u);
  K2 p1 = ctf(root.a, root.b, 1u, 3u);
  K2 k0{p0.a, p1.a};
  K2 kl{p0.b, p1.b};
#endif
  t.s0k[0] = k0.a; t.s0k[1] = k0.b;
  K2 k = kl;
  for (int s = 0; s < kSweeps; ++s) {
#if PARTITIONABLE
    K2 kn = ctf(k.a, k.b, 0u, 0u);
    K2 k1 = ctf(k.a, k.b, 0u, 1u);
    K2 k2 = ctf(k.a, k.b, 0u, 2u);
#else
    K2 q0 = ctf(k.a, k.b, 0u, 3u);
    K2 q1 = ctf(k.a, k.b, 1u, 4u);
    K2 q2 = ctf(k.a, k.b, 2u, 5u);
    K2 kn{q0.a, q1.a};
    K2 k1{q2.a, q0.b};
    K2 k2{q1.b, q2.b};
#endif
    t.sk[s][0] = k1.a; t.sk[s][1] = k1.b;
    t.sk[s][2] = k2.a; t.sk[s][3] = k2.b;
    k = kn;
  }
  return t;
}

__constant__ KeyTable g_keys = make_keys();

__device__ __forceinline__ uint32_t rng_bits32(uint32_t ka, uint32_t kb, uint32_t m) {
#if PARTITIONABLE
  K2 r = ctf(ka, kb, 0u, m);
  return r.a ^ r.b;
#else
  constexpr uint32_t H = (uint32_t)(kB * kN / 2);
  uint32_t p = (m < H) ? m : (m - H);
  K2 r = ctf(ka, kb, p, p + H);
  return (m < H) ? r.a : r.b;
#endif
}

__device__ __forceinline__ float bits_to_uniform(uint32_t bits) {
  // jax: bitcast(bits >> 9 | 0x3f800000) - 1.0
  return __uint_as_float((bits >> 9) | 0x3f800000u) - 1.0f;
}

// prep: betas + coalesced-permuted J.
// float4 idx = rh*8192 + c*256 + slot*64 + l2, comp = f&3
//   where rh=i>>7, l2=(i&127)>>1, r=i&1, c=j>>3, f=j&7, slot=r*2+(f>>2);
//   holds Jsym[rh*128 + 2*l2 + r][8c + 4*(slot&1) + comp].
// A load of (rh,c,slot) across 64 lanes (l2=lane) reads 64 contiguous
// float4 = 1 KB = 16 cachelines.
__global__ void prep_kernel(const float* __restrict__ gamma,
                            float* __restrict__ jp,
                            float* __restrict__ betas) {
  int e = blockIdx.x * blockDim.x + threadIdx.x;   // 0..65535
  int i = e / kN, j = e % kN;
  float v = 0.0f;
  if (i < j) v = gamma[i * kN + j];
  else if (i > j) v = gamma[j * kN + i];
  int rh = i >> 7, l2 = (i & 127) >> 1, r = i & 1, c = j >> 3, f = j & 7;
  int slot = r * 2 + (f >> 2);
  jp[(((size_t)rh * 8192 + c * 256 + slot * 64 + l2) << 2) + (f & 3)] = v;
  if (e < kSweeps) {
    double lo = log(0.1), hi = log(5.0);
    betas[e] = (float)exp(lo + (hi - lo) * (double)e / (double)(kSweeps - 1));
  }
}

// One VALU op per element: f32 fma with the f16 spin operand converted in-op.
// Conversion of +-1.0h to f32 is exact, then fp32 fma -> bit-identical to
// fmaf(+-1.0f, J, acc). op_sel picks lo/hi half of the packed u32.
#define FMIX_LO(a, w, j)                                                      \
  asm("v_fma_mix_f32 %0, %1, %2, %0 op_sel:[0,0,0] op_sel_hi:[1,0,0]"         \
      : "+v"(a) : "v"(w), "v"(j))
#define FMIX_HI(a, w, j)                                                      \
  asm("v_fma_mix_f32 %0, %1, %2, %0 op_sel:[1,0,0] op_sel_hi:[1,0,0]"         \
      : "+v"(a) : "v"(w), "v"(j))

__global__ __launch_bounds__(512) void anneal_kernel(
    const float* __restrict__ thetas, const float* __restrict__ jp,
    const float* __restrict__ betas, float* __restrict__ out) {
  // fp16 spins (+1.0h=0x3C00, -1.0h=0xBC00), [buf][g][row], dbuf: 16 KiB
  __shared__ __align__(16) unsigned short sh_h[2][kSamp][kN];
  // packed randoms w = ((b1>>9)<<1)|(b2>>31), one u32/site, dbuf: 32 KiB
  __shared__ __align__(16) uint32_t sh_rand[2][kSamp * kN];
  __shared__ float sh_red[kSamp][4];

  const int tid = threadIdx.x;
  const int lane = tid & 63;
  const int wvid = tid >> 6;                     // wave 0..7 -> SIMD wvid%4
  const bool consumer = (wvid < 4);
  const int b0 = blockIdx.x * kSamp;             // first sample of block

  int cur = 0;

  if (consumer) {
    const int cw = wvid;                         // consumer wave 0..3
    const int oct = cw & 1;                      // sample octet 0/1
    const int rh = cw >> 1;                      // row half 0/1
    const int gbase = oct * 8;                   // first sample of octet
    const int row0 = rh * 128 + 2 * lane;        // rows row0, row0+1

    // th_[2g+r] = theta of (sample gbase+g, row r); sreg[g] = fp16 spin pair
    float th_[16];
    uint32_t sreg[8];
#pragma unroll
    for (int g = 0; g < 8; ++g) {
      float2 t2 = *(const float2*)&thetas[(b0 + gbase + g) * kN + row0];
      th_[2 * g] = t2.x; th_[2 * g + 1] = t2.y;
    }
    // s0 = where(bernoulli(k0, 0.5), 1, -1) ; bernoulli = uniform < 0.5
#pragma unroll
    for (int g = 0; g < 8; ++g) {
      uint32_t m0 = (uint32_t)((b0 + gbase + g) * kN + row0);
      float u0 = bits_to_uniform(rng_bits32(g_keys.s0k[0], g_keys.s0k[1], m0));
      float u1 = bits_to_uniform(rng_bits32(g_keys.s0k[0], g_keys.s0k[1], m0 + 1));
      uint32_t pk = ((u0 < 0.5f) ? 0x3C00u : 0xBC00u) |
                    (((u1 < 0.5f) ? 0x3C00u : 0xBC00u) << 16);
      sreg[g] = pk;
      *(uint32_t*)&sh_h[0][gbase + g][row0] = pk;
    }
    __syncthreads();

    // coalesced J slice: slot s of chunk c at jpt[c*256 + s*64] (lane-contig)
    const float4* __restrict__ jpt =
        (const float4*)jp + (size_t)rh * 8192 + (size_t)lane;

#define LDSPIN(g, c) (*(const uint4*)&sh_h[cur][gbase + (g)][(c) * 8])
    // consume chunk (8 j) for 8 samples x 2 rows: 128 fma_mix, j ascending
#define CONSUME2(W, Q0, Q1, Q2, Q3)                                           \
  _Pragma("unroll")                                                           \
  for (int g = 0; g < 8; ++g) {                                               \
    FMIX_LO(acc[2*g], W[g].x, Q0.x); FMIX_HI(acc[2*g], W[g].x, Q0.y);         \
    FMIX_LO(acc[2*g], W[g].y, Q0.z); FMIX_HI(acc[2*g], W[g].y, Q0.w);         \
    FMIX_LO(acc[2*g], W[g].z, Q1.x); FMIX_HI(acc[2*g], W[g].z, Q1.y);         \
    FMIX_LO(acc[2*g], W[g].w, Q1.z); FMIX_HI(acc[2*g], W[g].w, Q1.w);         \
    FMIX_LO(acc[2*g+1], W[g].x, Q2.x); FMIX_HI(acc[2*g+1], W[g].x, Q2.y);     \
    FMIX_LO(acc[2*g+1], W[g].y, Q2.z); FMIX_HI(acc[2*g+1], W[g].y, Q2.w);     \
    FMIX_LO(acc[2*g+1], W[g].z, Q3.x); FMIX_HI(acc[2*g+1], W[g].z, Q3.y);     \
    FMIX_LO(acc[2*g+1], W[g].w, Q3.z); FMIX_HI(acc[2*g+1], W[g].w, Q3.w);     \
  }
    // matvec body as a statement macro so the A/B pipeline shape is fixed
#define MATVEC(acc)                                                           \
  {                                                                           \
    uint4 A[8], Bw[8];                                                        \
    float4 a0, a1, a2, a3, b0_, b1_, b2_, b3_;                                \
    _Pragma("unroll")                                                         \
    for (int g = 0; g < 8; ++g) A[g] = LDSPIN(g, 0);                          \
    a0 = jpt[0]; a1 = jpt[64]; a2 = jpt[128]; a3 = jpt[192];                  \
    _Pragma("unroll 1")                                                       \
    for (int k = 0; k < 15; ++k) {                                            \
      const int c = 2 * k;                                                    \
      _Pragma("unroll")                                                       \
      for (int g = 0; g < 8; ++g) Bw[g] = LDSPIN(g, c + 1);                   \
      b0_ = jpt[(c + 1) * 256 + 0];   b1_ = jpt[(c + 1) * 256 + 64];          \
      b2_ = jpt[(c + 1) * 256 + 128]; b3_ = jpt[(c + 1) * 256 + 192];         \
      CONSUME2(A, a0, a1, a2, a3)                                             \
      _Pragma("unroll")                                                       \
      for (int g = 0; g < 8; ++g) A[g] = LDSPIN(g, c + 2);                    \
      a0 = jpt[(c + 2) * 256 + 0];   a1 = jpt[(c + 2) * 256 + 64];            \
      a2 = jpt[(c + 2) * 256 + 128]; a3 = jpt[(c + 2) * 256 + 192];           \
      CONSUME2(Bw, b0_, b1_, b2_, b3_)                                        \
    }                                                                         \
    _Pragma("unroll")                                                         \
    for (int g = 0; g < 8; ++g) Bw[g] = LDSPIN(g, 31);                        \
    b0_ = jpt[31 * 256 + 0];   b1_ = jpt[31 * 256 + 64];                      \
    b2_ = jpt[31 * 256 + 128]; b3_ = jpt[31 * 256 + 192];                     \
    CONSUME2(A, a0, a1, a2, a3)                                               \
    CONSUME2(Bw, b0_, b1_, b2_, b3_)                                          \
  }

#pragma unroll 1
    for (int t = 0; t < kSweeps; ++t) {
      const float beta = betas[t];
      // randoms for this sweep (produced last sweep / prologue): 2 sites/g
      uint2 wp[8];
      {
        const uint32_t* __restrict__ rb =
            &sh_rand[t & 1][gbase * kN + rh * 128 + 2 * lane];
#pragma unroll
        for (int g = 0; g < 8; ++g)
          wp[g] = *(const uint2*)&rb[g * kN];
      }

      float acc[16];
#pragma unroll
      for (int x = 0; x < 16; ++x) acc[x] = 0.0f;
      MATVEC(acc)

#pragma unroll
      for (int g = 0; g < 8; ++g) {
        uint32_t pk = sreg[g];
        float s0f = __uint_as_float(0x3F800000u | ((pk << 16) & 0x80000000u));
        float s1f = __uint_as_float(0x3F800000u | (pk & 0x80000000u));
        float l0 = th_[2 * g] + acc[2 * g];
        float l1 = th_[2 * g + 1] + acc[2 * g + 1];
        float d0 = -2.0f * s0f * l0;       // exact: (-2*s) power of two
        float d1 = -2.0f * s1f * l1;
        float p0 = expf(-beta * d0);
        float p1 = expf(-beta * d1);
        float u0 = __uint_as_float((wp[g].x >> 1) | 0x3f800000u) - 1.0f;
        float u1 = __uint_as_float((wp[g].y >> 1) | 0x3f800000u) - 1.0f;
        uint32_t msk = 0u;
        if ((u0 < p0) && ((wp[g].x & 1u) == 0u)) msk |= 0x8000u;
        if ((u1 < p1) && ((wp[g].y & 1u) == 0u)) msk |= 0x80000000u;
        pk ^= msk;                          // flip = fp16 sign flip
        sreg[g] = pk;
        *(uint32_t*)&sh_h[cur ^ 1][gbase + g][row0] = pk;
      }
      __syncthreads();
      cur ^= 1;
    }

    // E_b = sum_i s_i*theta_i + 0.5 * sum_i s_i * (Jsym s)_i
    {
      float acc[16];
#pragma unroll
      for (int x = 0; x < 16; ++x) acc[x] = 0.0f;
      MATVEC(acc)

#pragma unroll
      for (int g = 0; g < 8; ++g) {
        uint32_t pk = sreg[g];
        float s0f = __uint_as_float(0x3F800000u | ((pk << 16) & 0x80000000u));
        float s1f = __uint_as_float(0x3F800000u | (pk & 0x80000000u));
        // identical expression to previous rounds: v = s*th + 0.5f*(s*acc)
        float x0 = s0f * th_[2 * g] + 0.5f * (s0f * acc[2 * g]);
        float x1 = s1f * th_[2 * g + 1] + 0.5f * (s1f * acc[2 * g + 1]);
        // slot-split tree == r10 == original 64-lane shfl tree
#pragma unroll
        for (int off = 16; off > 0; off >>= 1) {
          x0 += __shfl_down(x0, off);
          x1 += __shfl_down(x1, off);
        }
        float v = x0 + x1;
        if (lane == 0)  sh_red[gbase + g][2 * rh + 0] = v;  // rows [rh*128,+64)
        if (lane == 32) sh_red[gbase + g][2 * rh + 1] = v;  // rows [rh*128+64,+64)
      }
    }
  } else {
    // ---------------- producer waves (4..7) ----------------
    // store instruction k covers sites pw*1024 + k*256 + lane*4 + 0..3:
    // lane-contiguous 16B -> conflict-free ds_write_b128.
    const int pw = wvid - 4;                       // 0..3
    {
      const uint32_t k1a = g_keys.sk[0][0], k1b = g_keys.sk[0][1];
      const uint32_t k2a = g_keys.sk[0][2], k2b = g_keys.sk[0][3];
#pragma unroll
      for (int k = 0; k < 4; ++k) {
        const uint32_t site = (uint32_t)(pw * 1024 + k * 256 + lane * 4);
        const uint32_t mb = (uint32_t)(b0 * kN) + site;
        uint32_t wv[4];
#pragma unroll
        for (int e = 0; e < 4; ++e) {
          uint32_t b1 = rng_bits32(k1a, k1b, mb + e);
          uint32_t b2 = rng_bits32(k2a, k2b, mb + e);
          wv[e] = ((b1 >> 9) << 1) | (b2 >> 31);
        }
        uint4 v; v.x = wv[0]; v.y = wv[1]; v.z = wv[2]; v.w = wv[3];
        *(uint4*)&sh_rand[0][site] = v;
      }
    }
    __syncthreads();

#pragma unroll 1
    for (int t = 0; t < kSweeps; ++t) {
      if (t + 1 < kSweeps) {
        const uint32_t k1a = g_keys.sk[t + 1][0], k1b = g_keys.sk[t + 1][1];
        const uint32_t k2a = g_keys.sk[t + 1][2], k2b = g_keys.sk[t + 1][3];
#pragma unroll
        for (int k = 0; k < 4; ++k) {
          const uint32_t site = (uint32_t)(pw * 1024 + k * 256 + lane * 4);
          const uint32_t mb = (uint32_t)(b0 * kN) + site;
          uint32_t wv[4];
#pragma unroll
          for (int e = 0; e < 4; ++e) {
            uint32_t b1 = rng_bits32(k1a, k1b, mb + e);
            uint32_t b2 = rng_bits32(k2a, k2b, mb + e);
            wv[e] = ((b1 >> 9) << 1) | (b2 >> 31);
          }
          uint4 v; v.x = wv[0]; v.y = wv[1]; v.z = wv[2]; v.w = wv[3];
          *(uint4*)&sh_rand[(t + 1) & 1][site] = v;
        }
      }
      __syncthreads();
    }
  }

  __syncthreads();
  if (tid < kSamp) {
    out[b0 + tid] =
        sh_red[tid][0] + sh_red[tid][1] + sh_red[tid][2] + sh_red[tid][3];
  }
}

}  // namespace

extern "C" void kernel_launch(void* const* d_in, const int* in_sizes, int n_in,
                              void* d_out, int out_size, void* d_ws, size_t ws_size,
                              hipStream_t stream) {
  const float* thetas = (const float*)d_in[0];   // [4096, 256]
  const float* gamma  = (const float*)d_in[1];   // [256, 256]
  char* ws = (char*)d_ws;
  float* jp    = (float*)ws;                               // 256 KiB
  float* betas = (float*)(ws + (size_t)kN * kN * 4);       // 800 B

  hipLaunchKernelGGL(prep_kernel, dim3(kN), dim3(kN), 0, stream,
                     gamma, jp, betas);
  hipLaunchKernelGGL(anneal_kernel, dim3(kBlocks), dim3(512), 0, stream,
                     thetas, jp, betas, (float*)d_out);
}

// Round 18
// 2178.037 us; speedup vs baseline: 1.1892x; 1.0163x over previous
//
#include <hip/hip_runtime.h>
#include <stdint.h>
#include <math.h>

// Replicate jax.random threefry2x32 exactly (jax_threefry_partitionable=True).
#define PARTITIONABLE 1

namespace {

constexpr int kB = 4096;
constexpr int kN = 256;
constexpr int kSweeps = 200;
constexpr int kSamp = 16;                // samples per block
constexpr int kBlocks = kB / kSamp;      // 256 blocks of 1024 threads -> 1/CU
// r13 with doubled waves/SIMD at identical per-CU work:
// block = 16 waves. Waves 0-7 consumers: wave cw owns samples quad*4..+3
// (quad=cw>>1) x row-half rh=cw&1, 2 rows/thread -- the r13 consumer with
// half the samples/wave (same total: 1024 spin-reads/CU/sweep, same J).
// Waves 8-15 producers: next sweep's threefry, 8 sites/thread.
// Wave w -> SIMD w%4: every SIMD runs 2 consumers + 2 producers, so when
// one consumer stalls on lgkmcnt the other issues -- r13's measured
// ~sum(VALU,LDS) should move toward max(VALU,LDS).

struct K2 { uint32_t a, b; };

__host__ __device__ constexpr uint32_t crotl(uint32_t x, int d) {
  return (x << d) | (x >> (32 - d));
}

// Threefry-2x32, 20 rounds, exactly as jax/_src/prng.py
__host__ __device__ constexpr K2 ctf(uint32_t k0, uint32_t k1, uint32_t c0, uint32_t c1) {
  uint32_t ks0 = k0, ks1 = k1, ks2 = k0 ^ k1 ^ 0x1BD11BDAu;
  uint32_t x0 = c0 + ks0, x1 = c1 + ks1;
  const int r0[4] = {13, 15, 26, 6};
  const int r1[4] = {17, 29, 16, 24};
  for (int i = 0; i < 4; ++i) { x0 += x1; x1 = crotl(x1, r0[i]); x1 ^= x0; }
  x0 += ks1; x1 += ks2 + 1u;
  for (int i = 0; i < 4; ++i) { x0 += x1; x1 = crotl(x1, r1[i]); x1 ^= x0; }
  x0 += ks2; x1 += ks0 + 2u;
  for (int i = 0; i < 4; ++i) { x0 += x1; x1 = crotl(x1, r0[i]); x1 ^= x0; }
  x0 += ks0; x1 += ks1 + 3u;
  for (int i = 0; i < 4; ++i) { x0 += x1; x1 = crotl(x1, r1[i]); x1 ^= x0; }
  x0 += ks1; x1 += ks2 + 4u;
  for (int i = 0; i < 4; ++i) { x0 += x1; x1 = crotl(x1, r0[i]); x1 ^= x0; }
  x0 += ks2; x1 += ks0 + 5u;
  return K2{x0, x1};
}

struct KeyTable {
  uint32_t s0k[2];               // key for initial spins (k0)
  uint32_t sk[kSweeps][4];       // per sweep: k1a,k1b (accept), k2a,k2b (mask)
};

constexpr KeyTable make_keys() {
  KeyTable t{};
  K2 root{0u, 42u};              // jax.random.key(42) -> (hi=0, lo=42)
#if PARTITIONABLE
  K2 k0 = ctf(root.a, root.b, 0u, 0u);
  K2 kl = ctf(root.a, root.b, 0u, 1u);
#else
  K2 p0 = ctf(root.a, root.b, 0u, 2u);
  K2 p1 = ctf(root.a, root.b, 1u, 3u);
  K2 k0{p0.a, p1.a};
  K2 kl{p0.b, p1.b};
#endif
  t.s0k[0] = k0.a; t.s0k[1] = k0.b;
  K2 k = kl;
  for (int s = 0; s < kSweeps; ++s) {
#if PARTITIONABLE
    K2 kn = ctf(k.a, k.b, 0u, 0u);
    K2 k1 = ctf(k.a, k.b, 0u, 1u);
    K2 k2 = ctf(k.a, k.b, 0u, 2u);
#else
    K2 q0 = ctf(k.a, k.b, 0u, 3u);
    K2 q1 = ctf(k.a, k.b, 1u, 4u);
    K2 q2 = ctf(k.a, k.b, 2u, 5u);
    K2 kn{q0.a, q1.a};
    K2 k1{q2.a, q0.b};
    K2 k2{q1.b, q2.b};
#endif
    t.sk[s][0] = k1.a; t.sk[s][1] = k1.b;
    t.sk[s][2] = k2.a; t.sk[s][3] = k2.b;
    k = kn;
  }
  return t;
}

__constant__ KeyTable g_keys = make_keys();

__device__ __forceinline__ uint32_t rng_bits32(uint32_t ka, uint32_t kb, uint32_t m) {
#if PARTITIONABLE
  K2 r = ctf(ka, kb, 0u, m);
  return r.a ^ r.b;
#else
  constexpr uint32_t H = (uint32_t)(kB * kN / 2);
  uint32_t p = (m < H) ? m : (m - H);
  K2 r = ctf(ka, kb, p, p + H);
  return (m < H) ? r.a : r.b;
#endif
}

__device__ __forceinline__ float bits_to_uniform(uint32_t bits) {
  // jax: bitcast(bits >> 9 | 0x3f800000) - 1.0
  return __uint_as_float((bits >> 9) | 0x3f800000u) - 1.0f;
}

// prep: betas + coalesced-permuted J (r13 layout, harness-verified).
// float4 idx = rh*8192 + c*256 + slot*64 + l2, comp = f&3
//   where rh=i>>7, l2=(i&127)>>1, r=i&1, c=j>>3, f=j&7, slot=r*2+(f>>2);
//   holds Jsym[rh*128 + 2*l2 + r][8c + 4*(slot&1) + comp].
// A load of (rh,c,slot) across 64 lanes (l2=lane) reads 64 contiguous
// float4 = 1 KB = 16 cachelines.
__global__ void prep_kernel(const float* __restrict__ gamma,
                            float* __restrict__ jp,
                            float* __restrict__ betas) {
  int e = blockIdx.x * blockDim.x + threadIdx.x;   // 0..65535
  int i = e / kN, j = e % kN;
  float v = 0.0f;
  if (i < j) v = gamma[i * kN + j];
  else if (i > j) v = gamma[j * kN + i];
  int rh = i >> 7, l2 = (i & 127) >> 1, r = i & 1, c = j >> 3, f = j & 7;
  int slot = r * 2 + (f >> 2);
  jp[(((size_t)rh * 8192 + c * 256 + slot * 64 + l2) << 2) + (f & 3)] = v;
  if (e < kSweeps) {
    double lo = log(0.1), hi = log(5.0);
    betas[e] = (float)exp(lo + (hi - lo) * (double)e / (double)(kSweeps - 1));
  }
}

// One VALU op per element: f32 fma with the f16 spin operand converted in-op.
// Conversion of +-1.0h to f32 is exact, then fp32 fma -> bit-identical to
// fmaf(+-1.0f, J, acc). op_sel picks lo/hi half of the packed u32.
#define FMIX_LO(a, w, j)                                                      \
  asm("v_fma_mix_f32 %0, %1, %2, %0 op_sel:[0,0,0] op_sel_hi:[1,0,0]"         \
      : "+v"(a) : "v"(w), "v"(j))
#define FMIX_HI(a, w, j)                                                      \
  asm("v_fma_mix_f32 %0, %1, %2, %0 op_sel:[1,0,0] op_sel_hi:[1,0,0]"         \
      : "+v"(a) : "v"(w), "v"(j))

__global__ __launch_bounds__(1024) void anneal_kernel(
    const float* __restrict__ thetas, const float* __restrict__ jp,
    const float* __restrict__ betas, float* __restrict__ out) {
  // fp16 spins (+1.0h=0x3C00, -1.0h=0xBC00), [buf][g][row], dbuf: 16 KiB
  __shared__ __align__(16) unsigned short sh_h[2][kSamp][kN];
  // packed randoms w = ((b1>>9)<<1)|(b2>>31), one u32/site, dbuf: 32 KiB
  __shared__ __align__(16) uint32_t sh_rand[2][kSamp * kN];
  __shared__ float sh_red[kSamp][4];

  const int tid = threadIdx.x;
  const int lane = tid & 63;
  const int wvid = tid >> 6;                     // wave 0..15 -> SIMD wvid%4
  const bool consumer = (wvid < 8);
  const int b0 = blockIdx.x * kSamp;             // first sample of block

  int cur = 0;

  if (consumer) {
    const int cw = wvid;                         // consumer wave 0..7
    const int rh = cw & 1;                       // row half 0/1
    const int quad = cw >> 1;                    // sample quad 0..3
    const int gbase = quad * 4;                  // first sample of quad
    const int row0 = rh * 128 + 2 * lane;        // rows row0, row0+1

    // th_[2g+r] = theta of (sample gbase+g, row r); sreg[g] = fp16 spin pair
    float th_[8];
    uint32_t sreg[4];
#pragma unroll
    for (int g = 0; g < 4; ++g) {
      float2 t2 = *(const float2*)&thetas[(b0 + gbase + g) * kN + row0];
      th_[2 * g] = t2.x; th_[2 * g + 1] = t2.y;
    }
    // s0 = where(bernoulli(k0, 0.5), 1, -1) ; bernoulli = uniform < 0.5
#pragma unroll
    for (int g = 0; g < 4; ++g) {
      uint32_t m0 = (uint32_t)((b0 + gbase + g) * kN + row0);
      float u0 = bits_to_uniform(rng_bits32(g_keys.s0k[0], g_keys.s0k[1], m0));
      float u1 = bits_to_uniform(rng_bits32(g_keys.s0k[0], g_keys.s0k[1], m0 + 1));
      uint32_t pk = ((u0 < 0.5f) ? 0x3C00u : 0xBC00u) |
                    (((u1 < 0.5f) ? 0x3C00u : 0xBC00u) << 16);
      sreg[g] = pk;
      *(uint32_t*)&sh_h[0][gbase + g][row0] = pk;
    }
    __syncthreads();

    // coalesced J slice: slot s of chunk c at jpt[c*256 + s*64] (lane-contig)
    const float4* __restrict__ jpt =
        (const float4*)jp + (size_t)rh * 8192 + (size_t)lane;

#define LDSPIN(g, c) (*(const uint4*)&sh_h[cur][gbase + (g)][(c) * 8])
    // consume chunk (8 j) for 4 samples x 2 rows: 64 fma_mix, j ascending
#define CONSUME2(W, Q0, Q1, Q2, Q3)                                           \
  _Pragma("unroll")                                                           \
  for (int g = 0; g < 4; ++g) {                                               \
    FMIX_LO(acc[2*g], W[g].x, Q0.x); FMIX_HI(acc[2*g], W[g].x, Q0.y);         \
    FMIX_LO(acc[2*g], W[g].y, Q0.z); FMIX_HI(acc[2*g], W[g].y, Q0.w);         \
    FMIX_LO(acc[2*g], W[g].z, Q1.x); FMIX_HI(acc[2*g], W[g].z, Q1.y);         \
    FMIX_LO(acc[2*g], W[g].w, Q1.z); FMIX_HI(acc[2*g], W[g].w, Q1.w);         \
    FMIX_LO(acc[2*g+1], W[g].x, Q2.x); FMIX_HI(acc[2*g+1], W[g].x, Q2.y);     \
    FMIX_LO(acc[2*g+1], W[g].y, Q2.z); FMIX_HI(acc[2*g+1], W[g].y, Q2.w);     \
    FMIX_LO(acc[2*g+1], W[g].z, Q3.x); FMIX_HI(acc[2*g+1], W[g].z, Q3.y);     \
    FMIX_LO(acc[2*g+1], W[g].w, Q3.z); FMIX_HI(acc[2*g+1], W[g].w, Q3.w);     \
  }
    // matvec body as a statement macro so the A/B pipeline shape is fixed
#define MATVEC(acc)                                                           \
  {                                                                           \
    uint4 A[4], Bw[4];                                                        \
    float4 a0, a1, a2, a3, b0_, b1_, b2_, b3_;                                \
    _Pragma("unroll")                                                         \
    for (int g = 0; g < 4; ++g) A[g] = LDSPIN(g, 0);                          \
    a0 = jpt[0]; a1 = jpt[64]; a2 = jpt[128]; a3 = jpt[192];                  \
    _Pragma("unroll 1")                                                       \
    for (int k = 0; k < 15; ++k) {                                            \
      const int c = 2 * k;                                                    \
      _Pragma("unroll")                                                       \
      for (int g = 0; g < 4; ++g) Bw[g] = LDSPIN(g, c + 1);                   \
      b0_ = jpt[(c + 1) * 256 + 0];   b1_ = jpt[(c + 1) * 256 + 64];          \
      b2_ = jpt[(c + 1) * 256 + 128]; b3_ = jpt[(c + 1) * 256 + 192];         \
      CONSUME2(A, a0, a1, a2, a3)                                             \
      _Pragma("unroll")                                                       \
      for (int g = 0; g < 4; ++g) A[g] = LDSPIN(g, c + 2);                    \
      a0 = jpt[(c + 2) * 256 + 0];   a1 = jpt[(c + 2) * 256 + 64];            \
      a2 = jpt[(c + 2) * 256 + 128]; a3 = jpt[(c + 2) * 256 + 192];           \
      CONSUME2(Bw, b0_, b1_, b2_, b3_)                                        \
    }                                                                         \
    _Pragma("unroll")                                                         \
    for (int g = 0; g < 4; ++g) Bw[g] = LDSPIN(g, 31);                        \
    b0_ = jpt[31 * 256 + 0];   b1_ = jpt[31 * 256 + 64];                      \
    b2_ = jpt[31 * 256 + 128]; b3_ = jpt[31 * 256 + 192];                     \
    CONSUME2(A, a0, a1, a2, a3)                                               \
    CONSUME2(Bw, b0_, b1_, b2_, b3_)                                          \
  }

#pragma unroll 1
    for (int t = 0; t < kSweeps; ++t) {
      const float beta = betas[t];
      // randoms for this sweep (produced last sweep / prologue): 2 sites/g
      uint2 wp[4];
      {
        const uint32_t* __restrict__ rb =
            &sh_rand[t & 1][gbase * kN + rh * 128 + 2 * lane];
#pragma unroll
        for (int g = 0; g < 4; ++g)
          wp[g] = *(const uint2*)&rb[g * kN];
      }

      float acc[8];
#pragma unroll
      for (int x = 0; x < 8; ++x) acc[x] = 0.0f;
      MATVEC(acc)

#pragma unroll
      for (int g = 0; g < 4; ++g) {
        uint32_t pk = sreg[g];
        float s0f = __uint_as_float(0x3F800000u | ((pk << 16) & 0x80000000u));
        float s1f = __uint_as_float(0x3F800000u | (pk & 0x80000000u));
        float l0 = th_[2 * g] + acc[2 * g];
        float l1 = th_[2 * g + 1] + acc[2 * g + 1];
        float d0 = -2.0f * s0f * l0;       // exact: (-2*s) power of two
        float d1 = -2.0f * s1f * l1;
        float p0 = expf(-beta * d0);
        float p1 = expf(-beta * d1);
        float u0 = __uint_as_float((wp[g].x >> 1) | 0x3f800000u) - 1.0f;
        float u1 = __uint_as_float((wp[g].y >> 1) | 0x3f800000u) - 1.0f;
        uint32_t msk = 0u;
        if ((u0 < p0) && ((wp[g].x & 1u) == 0u)) msk |= 0x8000u;
        if ((u1 < p1) && ((wp[g].y & 1u) == 0u)) msk |= 0x80000000u;
        pk ^= msk;                          // flip = fp16 sign flip
        sreg[g] = pk;
        *(uint32_t*)&sh_h[cur ^ 1][gbase + g][row0] = pk;
      }
      __syncthreads();
      cur ^= 1;
    }

    // E_b = sum_i s_i*theta_i + 0.5 * sum_i s_i * (Jsym s)_i
    {
      float acc[8];
#pragma unroll
      for (int x = 0; x < 8; ++x) acc[x] = 0.0f;
      MATVEC(acc)

#pragma unroll
      for (int g = 0; g < 4; ++g) {
        uint32_t pk = sreg[g];
        float s0f = __uint_as_float(0x3F800000u | ((pk << 16) & 0x80000000u));
        float s1f = __uint_as_float(0x3F800000u | (pk & 0x80000000u));
        // identical expression to previous rounds: v = s*th + 0.5f*(s*acc)
        float x0 = s0f * th_[2 * g] + 0.5f * (s0f * acc[2 * g]);
        float x1 = s1f * th_[2 * g + 1] + 0.5f * (s1f * acc[2 * g + 1]);
        // slot-split tree == r13 == original 64-lane shfl tree
#pragma unroll
        for (int off = 16; off > 0; off >>= 1) {
          x0 += __shfl_down(x0, off);
          x1 += __shfl_down(x1, off);
        }
        float v = x0 + x1;
        if (lane == 0)  sh_red[gbase + g][2 * rh + 0] = v;  // rows [rh*128,+64)
        if (lane == 32) sh_red[gbase + g][2 * rh + 1] = v;  // rows [rh*128+64,+64)
      }
    }
  } else {
    // ---------------- producer waves (8..15) ----------------
    // store instruction k covers sites pw*512 + k*256 + lane*4 + 0..3:
    // lane-contiguous 16B -> conflict-free ds_write_b128. 8 sites/thread.
    const int pw = wvid - 8;                       // 0..7
    {
      const uint32_t k1a = g_keys.sk[0][0], k1b = g_keys.sk[0][1];
      const uint32_t k2a = g_keys.sk[0][2], k2b = g_keys.sk[0][3];
#pragma unroll
      for (int k = 0; k < 2; ++k) {
        const uint32_t site = (uint32_t)(pw * 512 + k * 256 + lane * 4);
        const uint32_t mb = (uint32_t)(b0 * kN) + site;
        uint32_t wv[4];
#pragma unroll
        for (int e = 0; e < 4; ++e) {
          uint32_t b1 = rng_bits32(k1a, k1b, mb + e);
          uint32_t b2 = rng_bits32(k2a, k2b, mb + e);
          wv[e] = ((b1 >> 9) << 1) | (b2 >> 31);
        }
        uint4 v; v.x = wv[0]; v.y = wv[1]; v.z = wv[2]; v.w = wv[3];
        *(uint4*)&sh_rand[0][site] = v;
      }
    }
    __syncthreads();

#pragma unroll 1
    for (int t = 0; t < kSweeps; ++t) {
      if (t + 1 < kSweeps) {
        const uint32_t k1a = g_keys.sk[t + 1][0], k1b = g_keys.sk[t + 1][1];
        const uint32_t k2a = g_keys.sk[t + 1][2], k2b = g_keys.sk[t + 1][3];
#pragma unroll
        for (int k = 0; k < 2; ++k) {
          const uint32_t site = (uint32_t)(pw * 512 + k * 256 + lane * 4);
          const uint32_t mb = (uint32_t)(b0 * kN) + site;
          uint32_t wv[4];
#pragma unroll
          for (int e = 0; e < 4; ++e) {
            uint32_t b1 = rng_bits32(k1a, k1b, mb + e);
            uint32_t b2 = rng_bits32(k2a, k2b, mb + e);
            wv[e] = ((b1 >> 9) << 1) | (b2 >> 31);
          }
          uint4 v; v.x = wv[0]; v.y = wv[1]; v.z = wv[2]; v.w = wv[3];
          *(uint4*)&sh_rand[(t + 1) & 1][site] = v;
        }
      }
      __syncthreads();
    }
  }

  __syncthreads();
  if (tid < kSamp) {
    out[b0 + tid] =
        sh_red[tid][0] + sh_red[tid][1] + sh_red[tid][2] + sh_red[tid][3];
  }
}

}  // namespace

extern "C" void kernel_launch(void* const* d_in, const int* in_sizes, int n_in,
                              void* d_out, int out_size, void* d_ws, size_t ws_size,
                              hipStream_t stream) {
  const float* thetas = (const float*)d_in[0];   // [4096, 256]
  const float* gamma  = (const float*)d_in[1];   // [256, 256]
  char* ws = (char*)d_ws;
  float* jp    = (float*)ws;                               // 256 KiB
  float* betas = (float*)(ws + (size_t)kN * kN * 4);       // 800 B

  hipLaunchKernelGGL(prep_kernel, dim3(kN), dim3(kN), 0, stream,
                     gamma, jp, betas);
  hipLaunchKernelGGL(anneal_kernel, dim3(kBlocks), dim3(1024), 0, stream,
                     thetas, jp, betas, (float*)d_out);
}